// Round 9
// baseline (2870.653 us; speedup 1.0000x reference)
//
#include <hip/hip_runtime.h>
#include <math.h>

#define NN 20000
#define EE 320000
#define NBINS 2048
#define HRANGE 64.0f
#define EPSF 1e-20f

typedef __attribute__((ext_vector_type(8))) short bf16x8;
typedef __attribute__((ext_vector_type(4))) float f32x4;

// ---------------- workspace layout (f32-slot offsets) ----------------------
// R8 bug: Pa/Pb were spaced 2.56M slots (fp8 sizing) but hold bf16 (need
// 5.12M each) -> Pa clobbered Pb clobbered pe. Fixed spacing below.
constexpr size_t OFF_DEG  = 0;                    // NN ints
constexpr size_t OFF_RS   = 20000;                // NN+1 ints (+pad)
constexpr size_t OFF_CUR  = 40008;                // NN ints
constexpr size_t OFF_EIX  = 60008;                // EE ints (CSR -> orig edge)
constexpr size_t OFF_GSD  = 380008;               // EE int2 (src,dst)
constexpr size_t OFF_B0   = 1020008;              // NN*128 bf16
constexpr size_t OFF_B1   = 2300008;              // NN*128 bf16
constexpr size_t OFF_PA   = 3580008;              // NN*512 bf16 (5.12M slots)
constexpr size_t OFF_PB   = 8700008;              // NN*512 bf16 (5.12M slots)
constexpr size_t OFF_PE   = 13820008;             // EE f32 (CSR order)
constexpr size_t OFF_DL   = 14140008;             // EE f32 (CSR order)
constexpr size_t OFF_HIST = 14460008;             // 2*NBINS f32
constexpr size_t OFF_SCAL = 14464104;             // 32 f32
constexpr size_t OFF_REP  = 14464136;             // 128 f32
constexpr size_t OFF_WT   = 14464264;             // 278528 bf16
// WT sub-offsets (bf16 units):
constexpr size_t WT_ENC0 = 0;         // 128x64 (n-major)
constexpr size_t WT_ENC  = 8192;      // 4 x 128x128
constexpr size_t WT_CLS0 = 73728;     // 128x64
constexpr size_t WT_CLS  = 81920;     // 4 x 128x128
constexpr size_t WT_EA1  = 147456;    // 512x256

__device__ __forceinline__ unsigned ordf(float f) {
  unsigned b = __float_as_uint(f);
  return (b >> 31) ? ~b : (b | 0x80000000u);
}
__device__ __forceinline__ float unordf(unsigned u) {
  unsigned b = (u >> 31) ? (u ^ 0x80000000u) : ~u;
  return __uint_as_float(b);
}
__device__ __forceinline__ ushort f2bf(float f) {   // RNE
  unsigned u = __float_as_uint(f);
  u += 0x7FFFu + ((u >> 16) & 1u);
  return (ushort)(u >> 16);
}
__device__ __forceinline__ float bf2f(ushort h) {
  return __uint_as_float(((unsigned)h) << 16);
}
__device__ __forceinline__ float bflo(unsigned v) { return __uint_as_float(v << 16); }
__device__ __forceinline__ float bfhi(unsigned v) { return __uint_as_float(v & 0xFFFF0000u); }

// ---------------- init ------------------------------------------------------
__global__ void init_ws(int* deg, int* cur, float* hist, float* scal, float* rep) {
  int i = blockIdx.x * blockDim.x + threadIdx.x;
  if (i < NN) { deg[i] = 0; cur[i] = 0; }
  if (i < 2 * NBINS) hist[i] = 0.f;
  if (i < 128) rep[i] = 0.f;
  if (i < 32) {
    if (i == 2)      ((unsigned*)scal)[2] = 0xFFFFFFFFu;
    else if (i == 3) ((unsigned*)scal)[3] = 0u;
    else scal[i] = 0.f;
  }
}

// ---------------- CSR build -------------------------------------------------
__global__ void count_deg(const int* __restrict__ dst, int* __restrict__ deg) {
  int e = blockIdx.x * 256 + threadIdx.x;
  if (e < EE) atomicAdd(&deg[dst[e]], 1);
}

__global__ __launch_bounds__(1024) void scan_deg(const int* __restrict__ deg,
                                                 int* __restrict__ rs) {
  __shared__ int ps[1024];
  const int t = threadIdx.x;
  const int base = t * 20;
  int loc[20];
  int s = 0;
#pragma unroll
  for (int j = 0; j < 20; ++j) {
    int idx = base + j;
    int v = (idx < NN) ? deg[idx] : 0;
    loc[j] = s;
    s += v;
  }
  ps[t] = s;
  __syncthreads();
  for (int off = 1; off < 1024; off <<= 1) {
    int x = (t >= off) ? ps[t - off] : 0;
    __syncthreads();
    ps[t] += x;
    __syncthreads();
  }
  const int excl = ps[t] - s;
#pragma unroll
  for (int j = 0; j < 20; ++j) {
    int idx = base + j;
    if (idx < NN) rs[idx] = excl + loc[j];
  }
  if (t == 1023) rs[NN] = ps[1023];
}

__global__ void fill_csr(const int* __restrict__ src, const int* __restrict__ dst,
                         const int* __restrict__ rs, int* __restrict__ cur,
                         int* __restrict__ eidx, int2* __restrict__ gsd) {
  int e = blockIdx.x * 256 + threadIdx.x;
  if (e < EE) {
    int d = dst[e];
    int p = atomicAdd(&cur[d], 1);
    int o = rs[d] + p;
    eidx[o] = e;
    gsd[o] = make_int2(src[e], d);
  }
}

// ---------------- all weight transposes in one kernel -----------------------
__global__ void transpose_all(const float* __restrict__ encW0, const float* __restrict__ encW,
                              const float* __restrict__ clsW0, const float* __restrict__ clsW,
                              const float* __restrict__ eaW1, ushort* __restrict__ Wt) {
  int i = blockIdx.x * 256 + threadIdx.x;
  if (i < 8192) {
    int k = i >> 7, n = i & 127;
    Wt[WT_ENC0 + n * 64 + k] = f2bf(encW0[i]);
  } else if (i < 73728) {
    int j = i - 8192;
    int l = j >> 14, r = j & 16383, k = r >> 7, n = r & 127;
    Wt[WT_ENC + l * 16384 + n * 128 + k] = f2bf(encW[j]);
  } else if (i < 81920) {
    int j = i - 73728;
    int k = j >> 7, n = j & 127;
    Wt[WT_CLS0 + n * 64 + k] = f2bf(clsW0[j]);
  } else if (i < 147456) {
    int j = i - 81920;
    int l = j >> 14, r = j & 16383, k = r >> 7, n = r & 127;
    Wt[WT_CLS + l * 16384 + n * 128 + k] = f2bf(clsW[j]);
  } else if (i < 278528) {
    int j = i - 147456;
    int k = j >> 9, n = j & 511;
    Wt[WT_EA1 + n * 256 + k] = f2bf(eaW1[j]);
  }
}

// ---------------- fused GIN layer, K=64 (fp32 x in, bf16 out) ---------------
// Edge-parallel: 32 nodes/block; block edge range strided over 32 8-lane
// groups; LDS f32 accumulator via atomicAdd (ds_add_f32). No serial chains.
template <bool USEDL>
__global__ __launch_bounds__(256) void fused_layer64(
    const float* __restrict__ X, ushort* __restrict__ C,
    const int2* __restrict__ gsd, const int* __restrict__ rs,
    const float* __restrict__ dl, const float* __restrict__ scal,
    const ushort* __restrict__ Bt, const float* __restrict__ bias) {
  __shared__ __align__(16) char smem[16896];
  float* accF = (float*)smem;                 // [32][68]
  const int tid = threadIdx.x;
  const int nb = blockIdx.x * 32;
  {
    const int r = tid >> 3, cb = (tid & 7) * 8;
    const float4* Xr = (const float4*)(X + (size_t)(nb + r) * 64 + cb);
    float4 s0 = Xr[0], s1 = Xr[1];
    float* dp = accF + r * 68 + cb;
    dp[0] = s0.x; dp[1] = s0.y; dp[2] = s0.z; dp[3] = s0.w;
    dp[4] = s1.x; dp[5] = s1.y; dp[6] = s1.z; dp[7] = s1.w;
  }
  float S = 0.f, sc = 1.f;
  if (USEDL) { S = scal[8]; sc = scal[9]; }
  __syncthreads();
  const int g = tid >> 3, l = tid & 7;
  const int eEnd = rs[nb + 32];
  int iA = rs[nb] + g, iB = iA + 32;
  int dA = 0, dB = 0;
  float rA = 0.f, rB = 0.f;
  float4 a0, a1, b0, b1;
  if (iA < eEnd) {
    int2 sd = gsd[iA]; dA = sd.y;
    if (USEDL) rA = dl[iA];
    const float4* R = (const float4*)(X + (size_t)sd.x * 64 + l * 8);
    a0 = R[0]; a1 = R[1];
  }
  if (iB < eEnd) {
    int2 sd = gsd[iB]; dB = sd.y;
    if (USEDL) rB = dl[iB];
    const float4* R = (const float4*)(X + (size_t)sd.x * 64 + l * 8);
    b0 = R[0]; b1 = R[1];
  }
  while (iA < eEnd) {
    int iC = iB + 32, dC = 0;
    float rC = 0.f;
    float4 c0, c1;
    if (iC < eEnd) {
      int2 sd = gsd[iC]; dC = sd.y;
      if (USEDL) rC = dl[iC];
      const float4* R = (const float4*)(X + (size_t)sd.x * 64 + l * 8);
      c0 = R[0]; c1 = R[1];
    }
    float* ac = accF + (dA - nb) * 68 + l * 8;
    float w = 1.f;
    if (USEDL) w = sc / (1.f + __expf(-(rA + S)));
    atomicAdd(&ac[0], w * a0.x); atomicAdd(&ac[1], w * a0.y);
    atomicAdd(&ac[2], w * a0.z); atomicAdd(&ac[3], w * a0.w);
    atomicAdd(&ac[4], w * a1.x); atomicAdd(&ac[5], w * a1.y);
    atomicAdd(&ac[6], w * a1.z); atomicAdd(&ac[7], w * a1.w);
    iA = iB; dA = dB; rA = rB; a0 = b0; a1 = b1;
    iB = iC; dB = dC; rB = rC; b0 = c0; b1 = c1;
  }
  __syncthreads();
  const int wave = tid >> 6, lane = tid & 63, quad = lane >> 4, l15 = lane & 15;
  const int mh = wave >> 1, nh = wave & 1;
  f32x4 acc[4] = {{0.f, 0.f, 0.f, 0.f}, {0.f, 0.f, 0.f, 0.f},
                  {0.f, 0.f, 0.f, 0.f}, {0.f, 0.f, 0.f, 0.f}};
#pragma unroll
  for (int k0 = 0; k0 < 64; k0 += 32) {
    const float* ap = accF + (mh * 16 + l15) * 68 + k0 + quad * 8;
    f32x4 u0 = *(const f32x4*)ap;
    f32x4 u1 = *(const f32x4*)(ap + 4);
    bf16x8 af;
    af[0] = (short)f2bf(u0[0]); af[1] = (short)f2bf(u0[1]);
    af[2] = (short)f2bf(u0[2]); af[3] = (short)f2bf(u0[3]);
    af[4] = (short)f2bf(u1[0]); af[5] = (short)f2bf(u1[1]);
    af[6] = (short)f2bf(u1[2]); af[7] = (short)f2bf(u1[3]);
#pragma unroll
    for (int t = 0; t < 4; ++t) {
      int bn = nh * 64 + t * 16 + l15;
      bf16x8 bf = *(const bf16x8*)(Bt + (size_t)bn * 64 + k0 + quad * 8);
      acc[t] = __builtin_amdgcn_mfma_f32_16x16x32_bf16(af, bf, acc[t], 0, 0, 0);
    }
  }
  __syncthreads();
  float (*Csm)[132] = (float(*)[132])smem;
#pragma unroll
  for (int t = 0; t < 4; ++t) {
    int lc = nh * 64 + t * 16 + l15;
    float bs = bias[lc];
#pragma unroll
    for (int r = 0; r < 4; ++r)
      Csm[mh * 16 + quad * 4 + r][lc] = fmaxf(acc[t][r] + bs, 0.f);
  }
  __syncthreads();
  const int r = tid >> 3, c0 = (tid & 7) * 16;
  ushort* Cp = C + (size_t)(nb + r) * 128 + c0;
#pragma unroll
  for (int k = 0; k < 4; ++k) {
    f32x4 vv = *(const f32x4*)&Csm[r][c0 + k * 4];
    ushort4 o;
    o.x = f2bf(vv[0]); o.y = f2bf(vv[1]); o.z = f2bf(vv[2]); o.w = f2bf(vv[3]);
    *(ushort4*)(Cp + k * 4) = o;
  }
}

// ---------------- fused GIN layer, K=128 (bf16 in/out) ----------------------
template <bool USEDL>
__global__ __launch_bounds__(256) void fused_layer128(
    const ushort* __restrict__ Xb, ushort* __restrict__ C,
    const int2* __restrict__ gsd, const int* __restrict__ rs,
    const float* __restrict__ dl, const float* __restrict__ scal,
    const ushort* __restrict__ Bt, const float* __restrict__ bias) {
  __shared__ __align__(16) char smem[16896];
  float* accF = (float*)smem;                 // [32][132]
  const int tid = threadIdx.x;
  const int nb = blockIdx.x * 32;
  {
    const int r = tid >> 3, cb = (tid & 7) * 16;
    const uint4* Xr = (const uint4*)(Xb + (size_t)(nb + r) * 128 + cb);
    uint4 s0 = Xr[0], s1 = Xr[1];
    float* dp = accF + r * 132 + cb;
    dp[0] = bflo(s0.x); dp[1] = bfhi(s0.x); dp[2] = bflo(s0.y); dp[3] = bfhi(s0.y);
    dp[4] = bflo(s0.z); dp[5] = bfhi(s0.z); dp[6] = bflo(s0.w); dp[7] = bfhi(s0.w);
    dp[8] = bflo(s1.x); dp[9] = bfhi(s1.x); dp[10] = bflo(s1.y); dp[11] = bfhi(s1.y);
    dp[12] = bflo(s1.z); dp[13] = bfhi(s1.z); dp[14] = bflo(s1.w); dp[15] = bfhi(s1.w);
  }
  float S = 0.f, sc = 1.f;
  if (USEDL) { S = scal[8]; sc = scal[9]; }
  __syncthreads();
  const int g = tid >> 3, l = tid & 7;
  const int eEnd = rs[nb + 32];
  int iA = rs[nb] + g, iB = iA + 32;
  int dA = 0, dB = 0;
  float rA = 0.f, rB = 0.f;
  uint4 a0, a1, b0, b1;
  if (iA < eEnd) {
    int2 sd = gsd[iA]; dA = sd.y;
    if (USEDL) rA = dl[iA];
    const uint4* R = (const uint4*)(Xb + (size_t)sd.x * 128 + l * 16);
    a0 = R[0]; a1 = R[1];
  }
  if (iB < eEnd) {
    int2 sd = gsd[iB]; dB = sd.y;
    if (USEDL) rB = dl[iB];
    const uint4* R = (const uint4*)(Xb + (size_t)sd.x * 128 + l * 16);
    b0 = R[0]; b1 = R[1];
  }
  while (iA < eEnd) {
    int iC = iB + 32, dC = 0;
    float rC = 0.f;
    uint4 c0, c1;
    if (iC < eEnd) {
      int2 sd = gsd[iC]; dC = sd.y;
      if (USEDL) rC = dl[iC];
      const uint4* R = (const uint4*)(Xb + (size_t)sd.x * 128 + l * 16);
      c0 = R[0]; c1 = R[1];
    }
    float* ac = accF + (dA - nb) * 132 + l * 16;
    float w = 1.f;
    if (USEDL) w = sc / (1.f + __expf(-(rA + S)));
    atomicAdd(&ac[0],  w * bflo(a0.x)); atomicAdd(&ac[1],  w * bfhi(a0.x));
    atomicAdd(&ac[2],  w * bflo(a0.y)); atomicAdd(&ac[3],  w * bfhi(a0.y));
    atomicAdd(&ac[4],  w * bflo(a0.z)); atomicAdd(&ac[5],  w * bfhi(a0.z));
    atomicAdd(&ac[6],  w * bflo(a0.w)); atomicAdd(&ac[7],  w * bfhi(a0.w));
    atomicAdd(&ac[8],  w * bflo(a1.x)); atomicAdd(&ac[9],  w * bfhi(a1.x));
    atomicAdd(&ac[10], w * bflo(a1.y)); atomicAdd(&ac[11], w * bfhi(a1.y));
    atomicAdd(&ac[12], w * bflo(a1.z)); atomicAdd(&ac[13], w * bfhi(a1.z));
    atomicAdd(&ac[14], w * bflo(a1.w)); atomicAdd(&ac[15], w * bfhi(a1.w));
    iA = iB; dA = dB; rA = rB; a0 = b0; a1 = b1;
    iB = iC; dB = dC; rB = rC; b0 = c0; b1 = c1;
  }
  __syncthreads();
  const int wave = tid >> 6, lane = tid & 63, quad = lane >> 4, l15 = lane & 15;
  const int mh = wave >> 1, nh = wave & 1;
  f32x4 acc[4] = {{0.f, 0.f, 0.f, 0.f}, {0.f, 0.f, 0.f, 0.f},
                  {0.f, 0.f, 0.f, 0.f}, {0.f, 0.f, 0.f, 0.f}};
#pragma unroll
  for (int k0 = 0; k0 < 128; k0 += 32) {
    const float* ap = accF + (mh * 16 + l15) * 132 + k0 + quad * 8;
    f32x4 u0 = *(const f32x4*)ap;
    f32x4 u1 = *(const f32x4*)(ap + 4);
    bf16x8 af;
    af[0] = (short)f2bf(u0[0]); af[1] = (short)f2bf(u0[1]);
    af[2] = (short)f2bf(u0[2]); af[3] = (short)f2bf(u0[3]);
    af[4] = (short)f2bf(u1[0]); af[5] = (short)f2bf(u1[1]);
    af[6] = (short)f2bf(u1[2]); af[7] = (short)f2bf(u1[3]);
#pragma unroll
    for (int t = 0; t < 4; ++t) {
      int bn = nh * 64 + t * 16 + l15;
      bf16x8 bf = *(const bf16x8*)(Bt + (size_t)bn * 128 + k0 + quad * 8);
      acc[t] = __builtin_amdgcn_mfma_f32_16x16x32_bf16(af, bf, acc[t], 0, 0, 0);
    }
  }
  __syncthreads();
  float (*Csm)[132] = (float(*)[132])smem;
#pragma unroll
  for (int t = 0; t < 4; ++t) {
    int lc = nh * 64 + t * 16 + l15;
    float bs = bias[lc];
#pragma unroll
    for (int r = 0; r < 4; ++r)
      Csm[mh * 16 + quad * 4 + r][lc] = fmaxf(acc[t][r] + bs, 0.f);
  }
  __syncthreads();
  const int r = tid >> 3, c0 = (tid & 7) * 16;
  ushort* Cp = C + (size_t)(nb + r) * 128 + c0;
#pragma unroll
  for (int k = 0; k < 4; ++k) {
    f32x4 vv = *(const f32x4*)&Csm[r][c0 + k * 4];
    ushort4 o;
    o.x = f2bf(vv[0]); o.y = f2bf(vv[1]); o.z = f2bf(vv[2]); o.w = f2bf(vv[3]);
    *(ushort4*)(Cp + k * 4) = o;
  }
}

// ---------------- Pa/Pb GEMM, bf16 output: grid (8, 625) --------------------
__global__ __launch_bounds__(256) void gemm_papb(
    const ushort* __restrict__ Hb, const ushort* __restrict__ W1t,
    const float* __restrict__ b1, ushort* __restrict__ Pa, ushort* __restrict__ Pb) {
  __shared__ float lds[32][132];
  const int tid = threadIdx.x;
  const int wave = tid >> 6, lane = tid & 63, quad = lane >> 4, l15 = lane & 15;
  const int mh = wave >> 1, nh = wave & 1;
  const bool isB = blockIdx.x >= 4;
  const int col0 = (blockIdx.x & 3) * 128;
  const int row0 = blockIdx.y * 32;
  const ushort* Bt = W1t + (isB ? 128 : 0);
  ushort* C = isB ? Pb : Pa;
  f32x4 acc[4] = {{0.f, 0.f, 0.f, 0.f}, {0.f, 0.f, 0.f, 0.f},
                  {0.f, 0.f, 0.f, 0.f}, {0.f, 0.f, 0.f, 0.f}};
  const ushort* Ap = Hb + (size_t)(row0 + mh * 16 + l15) * 128 + quad * 8;
#pragma unroll
  for (int k0 = 0; k0 < 128; k0 += 32) {
    bf16x8 af = *(const bf16x8*)(Ap + k0);
#pragma unroll
    for (int t = 0; t < 4; ++t) {
      int bn = col0 + nh * 64 + t * 16 + l15;
      bf16x8 bf = *(const bf16x8*)(Bt + (size_t)bn * 256 + k0 + quad * 8);
      acc[t] = __builtin_amdgcn_mfma_f32_16x16x32_bf16(af, bf, acc[t], 0, 0, 0);
    }
  }
#pragma unroll
  for (int t = 0; t < 4; ++t) {
    int lc = nh * 64 + t * 16 + l15;
    float bs = isB ? 0.f : b1[col0 + lc];
#pragma unroll
    for (int r = 0; r < 4; ++r)
      lds[mh * 16 + quad * 4 + r][lc] = acc[t][r] + bs;
  }
  __syncthreads();
  const int r = tid >> 3, c0 = (tid & 7) * 16;
  ushort* Cp = C + (size_t)(row0 + r) * 512 + col0 + c0;
#pragma unroll
  for (int k = 0; k < 4; ++k) {
    f32x4 v = *(const f32x4*)&lds[r][c0 + k * 4];
    ushort4 o;
    o.x = f2bf(v[0]); o.y = f2bf(v[1]); o.z = f2bf(v[2]); o.w = f2bf(v[3]);
    *(ushort4*)(Cp + k * 4) = o;
  }
}

// ---------------- edge MLP layer 2 (bf16), edge-parallel + fused stats ------
// Block: 8 nodes, edge range strided over 8 half-waves (32 lanes/edge).
__global__ __launch_bounds__(256) void edge_pe_csr(
    const ushort* __restrict__ Pa, const ushort* __restrict__ Pb,
    const int2* __restrict__ gsd, const int* __restrict__ rs,
    const float* __restrict__ W2, const float* __restrict__ b2,
    float* __restrict__ pe, float* __restrict__ scal) {
  __shared__ float st[8][4];
  const int tid = threadIdx.x;
  const int hl = tid & 31;
  const int hw = tid >> 5;
  const int nb = blockIdx.x * 8;
  float w[16];
  {
    const float4* w2v = (const float4*)(W2 + hl * 16);
#pragma unroll
    for (int q = 0; q < 4; ++q) {
      float4 t = w2v[q];
      w[q * 4 + 0] = t.x; w[q * 4 + 1] = t.y; w[q * 4 + 2] = t.z; w[q * 4 + 3] = t.w;
    }
  }
  const float b2v = b2[0];
  const int eEnd = rs[nb + 8];
  float s = 0.f, qq = 0.f, mn = 3.0e38f, mx = -3.0e38f;
  int iA = rs[nb] + hw, iB = iA + 8;
  uint4 aA0, aA1, bA0, bA1, aB0, aB1, bB0, bB1;
  if (iA < eEnd) {
    int2 sd = gsd[iA];
    const uint4* RA = (const uint4*)(Pa + (size_t)sd.x * 512 + hl * 16);
    const uint4* RB = (const uint4*)(Pb + (size_t)sd.y * 512 + hl * 16);
    aA0 = RA[0]; aA1 = RA[1]; bA0 = RB[0]; bA1 = RB[1];
  }
  if (iB < eEnd) {
    int2 sd = gsd[iB];
    const uint4* RA = (const uint4*)(Pa + (size_t)sd.x * 512 + hl * 16);
    const uint4* RB = (const uint4*)(Pb + (size_t)sd.y * 512 + hl * 16);
    aB0 = RA[0]; aB1 = RA[1]; bB0 = RB[0]; bB1 = RB[1];
  }
  while (iA < eEnd) {
    int iC = iB + 8;
    uint4 aC0, aC1, bC0, bC1;
    if (iC < eEnd) {
      int2 sd = gsd[iC];
      const uint4* RA = (const uint4*)(Pa + (size_t)sd.x * 512 + hl * 16);
      const uint4* RB = (const uint4*)(Pb + (size_t)sd.y * 512 + hl * 16);
      aC0 = RA[0]; aC1 = RA[1]; bC0 = RB[0]; bC1 = RB[1];
    }
    float pa[16], pb[16];
    pa[0] = bflo(aA0.x); pa[1] = bfhi(aA0.x); pa[2] = bflo(aA0.y); pa[3] = bfhi(aA0.y);
    pa[4] = bflo(aA0.z); pa[5] = bfhi(aA0.z); pa[6] = bflo(aA0.w); pa[7] = bfhi(aA0.w);
    pa[8] = bflo(aA1.x); pa[9] = bfhi(aA1.x); pa[10] = bflo(aA1.y); pa[11] = bfhi(aA1.y);
    pa[12] = bflo(aA1.z); pa[13] = bfhi(aA1.z); pa[14] = bflo(aA1.w); pa[15] = bfhi(aA1.w);
    pb[0] = bflo(bA0.x); pb[1] = bfhi(bA0.x); pb[2] = bflo(bA0.y); pb[3] = bfhi(bA0.y);
    pb[4] = bflo(bA0.z); pb[5] = bfhi(bA0.z); pb[6] = bflo(bA0.w); pb[7] = bfhi(bA0.w);
    pb[8] = bflo(bA1.x); pb[9] = bfhi(bA1.x); pb[10] = bflo(bA1.y); pb[11] = bfhi(bA1.y);
    pb[12] = bflo(bA1.z); pb[13] = bfhi(bA1.z); pb[14] = bflo(bA1.w); pb[15] = bfhi(bA1.w);
    float acc = 0.f;
#pragma unroll
    for (int j = 0; j < 16; ++j) acc += fmaxf(pa[j] + pb[j], 0.f) * w[j];
#pragma unroll
    for (int off = 16; off; off >>= 1) acc += __shfl_xor(acc, off);
    if (hl == 0) {
      float v = acc + b2v;
      pe[iA] = v;
      s += v; qq = fmaf(v, v, qq);
      mn = fminf(mn, v); mx = fmaxf(mx, v);
    }
    iA = iB; aA0 = aB0; aA1 = aB1; bA0 = bB0; bA1 = bB1;
    iB = iC; aB0 = aC0; aB1 = aC1; bB0 = bC0; bB1 = bC1;
  }
  if (hl == 0) { st[hw][0] = s; st[hw][1] = qq; st[hw][2] = mn; st[hw][3] = mx; }
  __syncthreads();
  if (tid == 0) {
    float ts = 0.f, tq = 0.f, tm = 3.0e38f, tM = -3.0e38f;
#pragma unroll
    for (int k = 0; k < 8; ++k) {
      ts += st[k][0]; tq += st[k][1];
      tm = fminf(tm, st[k][2]); tM = fmaxf(tM, st[k][3]);
    }
    unsafeAtomicAdd(&scal[0], ts);
    unsafeAtomicAdd(&scal[1], tq);
    atomicMin((unsigned*)scal + 2, ordf(tm));
    atomicMax((unsigned*)scal + 3, ordf(tM));
  }
}

// ---------------- delta + histogram (CSR order; u gathered via eidx) --------
__global__ __launch_bounds__(256) void edge_delta_hist(
    const float* __restrict__ pe, const float* __restrict__ u,
    const int* __restrict__ eidx, float* __restrict__ delta,
    float* __restrict__ hist, const float* __restrict__ scal) {
  __shared__ float cnt_s[NBINS], sum_s[NBINS];
  for (int b = threadIdx.x; b < NBINS; b += 256) { cnt_s[b] = 0.f; sum_s[b] = 0.f; }
  float sum = scal[0], ssq = scal[1];
  float mn = unordf(((const unsigned*)scal)[2]);
  float mx = unordf(((const unsigned*)scal)[3]);
  float mu = sum / (float)EE;
  float var = (ssq - sum * sum / (float)EE) / (float)(EE - 1);
  float istd = rsqrtf(fmaxf(var, 1e-30f));
  float shift = (mn - mu) * istd + (mx - mu) * istd;
  __syncthreads();
  for (int i = blockIdx.x * 256 + threadIdx.x; i < EE; i += gridDim.x * 256) {
    float uu = u[eidx[i]];
    float atts = (pe[i] - mu) * istd;
    float g = -logf(-logf(uu + EPSF) + EPSF);
    float dv = 2.0f * (atts + g) - shift;
    delta[i] = dv;
    float dcl = fminf(fmaxf(dv, -HRANGE), HRANGE * 0.9999f);
    int b = (int)((dcl + HRANGE) * ((float)NBINS / (2.0f * HRANGE)));
    b = min(max(b, 0), NBINS - 1);
    atomicAdd(&cnt_s[b], 1.0f);
    atomicAdd(&sum_s[b], dcl);
  }
  __syncthreads();
  for (int b = threadIdx.x; b < NBINS; b += 256) {
    float c = cnt_s[b];
    if (c != 0.f) {
      unsafeAtomicAdd(&hist[b], c);
      unsafeAtomicAdd(&hist[NBINS + b], sum_s[b]);
    }
  }
}

// ---------------- scalar Sinkhorn recursion (single wave) -------------------
__global__ __launch_bounds__(64) void sinkhorn_iter(const float* __restrict__ hist,
                                                    float* __restrict__ scal) {
  const int lane = threadIdx.x;
  float cnt[32], mean[32];
#pragma unroll
  for (int b = 0; b < 32; ++b) {
    int idx = b * 64 + lane;
    float c = hist[idx];
    cnt[b] = c;
    mean[b] = (c > 0.f) ? hist[NBINS + idx] / c : 0.f;
  }
  const float LRD = -1.0986122886681098f;
  float S = 0.f, Zfin = 0.f;
  for (int it = 0; it < 30; ++it) {
    float p = 0.f;
#pragma unroll
    for (int b = 0; b < 32; ++b)
      if (cnt[b] > 0.f) p += cnt[b] / (1.f + expf(-(mean[b] + S)));
#pragma unroll
    for (int off = 32; off; off >>= 1) p += __shfl_xor(p, off);
    if (it < 29)
      S += logf(fmaxf((float)EE - p, 1.0f)) - logf(p) + LRD;
    else
      Zfin = p;
  }
  if (lane == 0) {
    scal[8] = S;
    scal[9] = ((float)EE * 0.25f) / Zfin;
  }
}

// ---------------- mean pooling + head ---------------------------------------
__global__ __launch_bounds__(128) void col_mean(const ushort* __restrict__ Hc,
                                                float* __restrict__ rep) {
  int c = threadIdx.x;
  const int g = gridDim.x;
  float p0 = 0.f, p1 = 0.f, p2 = 0.f, p3 = 0.f;
  int n = blockIdx.x;
  for (; n + 3 * g < NN; n += 4 * g) {
    p0 += bf2f(Hc[(size_t)n * 128 + c]);
    p1 += bf2f(Hc[(size_t)(n + g) * 128 + c]);
    p2 += bf2f(Hc[(size_t)(n + 2 * g) * 128 + c]);
    p3 += bf2f(Hc[(size_t)(n + 3 * g) * 128 + c]);
  }
  for (; n < NN; n += g) p0 += bf2f(Hc[(size_t)n * 128 + c]);
  unsafeAtomicAdd(&rep[c], (p0 + p1) + (p2 + p3));
}

__global__ __launch_bounds__(128) void head_kernel(const float* __restrict__ repsum,
                                                   const float* __restrict__ hW,
                                                   const float* __restrict__ hb,
                                                   float* __restrict__ out) {
  __shared__ float rep[128];
  int tid = threadIdx.x;
  if (tid < 128) rep[tid] = repsum[tid] * (1.0f / (float)NN);
  __syncthreads();
  if (tid < 10) {
    float a = hb[tid];
#pragma unroll
    for (int c = 0; c < 128; c++) a = fmaf(rep[c], hW[c * 10 + tid], a);
    out[tid] = a;
  }
}

// ---------------- launch ----------------------------------------------------
extern "C" void kernel_launch(void* const* d_in, const int* in_sizes, int n_in,
                              void* d_out, int out_size, void* d_ws, size_t ws_size,
                              hipStream_t stream) {
  const float* x      = (const float*)d_in[0];
  const int*   ei     = (const int*)d_in[1];
  const float* u      = (const float*)d_in[2];
  const float* enc_W0 = (const float*)d_in[3];
  const float* enc_b0 = (const float*)d_in[4];
  const float* enc_W  = (const float*)d_in[5];
  const float* enc_b  = (const float*)d_in[6];
  const float* ea_W1  = (const float*)d_in[7];
  const float* ea_b1  = (const float*)d_in[8];
  const float* ea_W2  = (const float*)d_in[9];
  const float* ea_b2  = (const float*)d_in[10];
  const float* cls_W0 = (const float*)d_in[11];
  const float* cls_b0 = (const float*)d_in[12];
  const float* cls_W  = (const float*)d_in[13];
  const float* cls_b  = (const float*)d_in[14];
  const float* head_W = (const float*)d_in[15];
  const float* head_b = (const float*)d_in[16];
  const int* src  = ei;
  const int* dstp = ei + EE;

  float* wsF = (float*)d_ws;
  int*   wsI = (int*)d_ws;
  int* deg  = wsI + OFF_DEG;
  int* rs   = wsI + OFF_RS;
  int* cur  = wsI + OFF_CUR;
  int* eix  = wsI + OFF_EIX;
  int2* gsd = (int2*)(wsI + OFF_GSD);
  ushort* B0 = (ushort*)(wsF + OFF_B0);
  ushort* B1 = (ushort*)(wsF + OFF_B1);
  ushort* Pa = (ushort*)(wsF + OFF_PA);
  ushort* Pb = (ushort*)(wsF + OFF_PB);
  float* pe   = wsF + OFF_PE;
  float* dl   = wsF + OFF_DL;
  float* hist = wsF + OFF_HIST;
  float* scal = wsF + OFF_SCAL;
  float* rep  = wsF + OFF_REP;
  ushort* Wt  = (ushort*)(wsF + OFF_WT);
  float* out = (float*)d_out;

  init_ws<<<(NN + 255) / 256, 256, 0, stream>>>(deg, cur, hist, scal, rep);
  count_deg<<<(EE + 255) / 256, 256, 0, stream>>>(dstp, deg);
  scan_deg<<<1, 1024, 0, stream>>>(deg, rs);
  fill_csr<<<(EE + 255) / 256, 256, 0, stream>>>(src, dstp, rs, cur, eix, gsd);
  transpose_all<<<1088, 256, 0, stream>>>(enc_W0, enc_W, cls_W0, cls_W, ea_W1, Wt);

  const int GB = NN / 32;  // 625

  // encoder GIN stack (att = 1)
  fused_layer64<false><<<GB, 256, 0, stream>>>(x, B0, gsd, rs, nullptr, scal,
                                               Wt + WT_ENC0, enc_b0);
  {
    ushort* in = B0; ushort* outb = B1;
    for (int l = 0; l < 4; l++) {
      fused_layer128<false><<<GB, 256, 0, stream>>>(in, outb, gsd, rs, nullptr, scal,
                                                    Wt + WT_ENC + (size_t)l * 16384,
                                                    enc_b + (size_t)l * 128);
      ushort* t = in; in = outb; outb = t;
    }
  }
  // encoder output in B0

  gemm_papb<<<dim3(8, GB), 256, 0, stream>>>(B0, Wt + WT_EA1, ea_b1, Pa, Pb);
  edge_pe_csr<<<NN / 8, 256, 0, stream>>>(Pa, Pb, gsd, rs, ea_W2, ea_b2, pe, scal);

  edge_delta_hist<<<256, 256, 0, stream>>>(pe, u, eix, dl, hist, scal);
  sinkhorn_iter<<<1, 64, 0, stream>>>(hist, scal);

  // classifier GIN stack (att = sc*sigmoid(dl+S), computed inline)
  fused_layer64<true><<<GB, 256, 0, stream>>>(x, B0, gsd, rs, dl, scal,
                                              Wt + WT_CLS0, cls_b0);
  {
    ushort* in = B0; ushort* outb = B1;
    for (int l = 0; l < 4; l++) {
      fused_layer128<true><<<GB, 256, 0, stream>>>(in, outb, gsd, rs, dl, scal,
                                                   Wt + WT_CLS + (size_t)l * 16384,
                                                   cls_b + (size_t)l * 128);
      ushort* t = in; in = outb; outb = t;
    }
  }

  col_mean<<<256, 128, 0, stream>>>(B0, rep);
  head_kernel<<<1, 128, 0, stream>>>(rep, head_W, head_b, out);
}

// Round 10
// 617.889 us; speedup vs baseline: 4.6459x; 4.6459x over previous
//
#include <hip/hip_runtime.h>
#include <math.h>

#define NN 20000
#define EE 320000
#define NBINS 2048
#define HRANGE 64.0f
#define EPSF 1e-20f

typedef __attribute__((ext_vector_type(8))) short bf16x8;
typedef __attribute__((ext_vector_type(4))) float f32x4;

// ---------------- workspace layout (f32-slot offsets) ----------------------
constexpr size_t OFF_DEG  = 0;                    // NN ints
constexpr size_t OFF_RS   = 20000;                // NN+1 ints (+pad)
constexpr size_t OFF_CUR  = 40008;                // NN ints
constexpr size_t OFF_EIX  = 60008;                // EE ints (CSR -> orig edge)
constexpr size_t OFF_GSD  = 380008;               // EE int2 (src,dst)
constexpr size_t OFF_B0   = 1020008;              // NN*128 bf16
constexpr size_t OFF_B1   = 2300008;              // NN*128 bf16
constexpr size_t OFF_PA   = 3580008;              // NN*512 bf16 (5.12M slots)
constexpr size_t OFF_PB   = 8700008;              // NN*512 bf16 (5.12M slots)
constexpr size_t OFF_PE   = 13820008;             // EE f32 (CSR order)
constexpr size_t OFF_DL   = 14140008;             // EE f32 (CSR order)
constexpr size_t OFF_HIST = 14460008;             // 2*NBINS f32
constexpr size_t OFF_SCAL = 14464104;             // 32 f32
constexpr size_t OFF_REP  = 14464136;             // 128 f32
constexpr size_t OFF_WT   = 14464264;             // 278528 bf16
// WT sub-offsets (bf16 units):
constexpr size_t WT_ENC0 = 0;         // 128x64 (n-major)
constexpr size_t WT_ENC  = 8192;      // 4 x 128x128
constexpr size_t WT_CLS0 = 73728;     // 128x64
constexpr size_t WT_CLS  = 81920;     // 4 x 128x128
constexpr size_t WT_EA1  = 147456;    // 512x256

__device__ __forceinline__ unsigned ordf(float f) {
  unsigned b = __float_as_uint(f);
  return (b >> 31) ? ~b : (b | 0x80000000u);
}
__device__ __forceinline__ float unordf(unsigned u) {
  unsigned b = (u >> 31) ? (u ^ 0x80000000u) : ~u;
  return __uint_as_float(b);
}
__device__ __forceinline__ ushort f2bf(float f) {   // RNE
  unsigned u = __float_as_uint(f);
  u += 0x7FFFu + ((u >> 16) & 1u);
  return (ushort)(u >> 16);
}
__device__ __forceinline__ unsigned pack2(float x, float y) {
  return (unsigned)f2bf(x) | ((unsigned)f2bf(y) << 16);
}
__device__ __forceinline__ float bf2f(ushort h) {
  return __uint_as_float(((unsigned)h) << 16);
}
__device__ __forceinline__ float bflo(unsigned v) { return __uint_as_float(v << 16); }
__device__ __forceinline__ float bfhi(unsigned v) { return __uint_as_float(v & 0xFFFF0000u); }

// ---------------- init ------------------------------------------------------
__global__ void init_ws(int* deg, int* cur, float* hist, float* scal, float* rep) {
  int i = blockIdx.x * blockDim.x + threadIdx.x;
  if (i < NN) { deg[i] = 0; cur[i] = 0; }
  if (i < 2 * NBINS) hist[i] = 0.f;
  if (i < 128) rep[i] = 0.f;
  if (i < 32) {
    if (i == 2)      ((unsigned*)scal)[2] = 0xFFFFFFFFu;
    else if (i == 3) ((unsigned*)scal)[3] = 0u;
    else scal[i] = 0.f;
  }
}

// ---------------- CSR build -------------------------------------------------
__global__ void count_deg(const int* __restrict__ dst, int* __restrict__ deg) {
  int e = blockIdx.x * 256 + threadIdx.x;
  if (e < EE) atomicAdd(&deg[dst[e]], 1);
}

__global__ __launch_bounds__(1024) void scan_deg(const int* __restrict__ deg,
                                                 int* __restrict__ rs) {
  __shared__ int ps[1024];
  const int t = threadIdx.x;
  const int base = t * 20;
  int loc[20];
  int s = 0;
#pragma unroll
  for (int j = 0; j < 20; ++j) {
    int idx = base + j;
    int v = (idx < NN) ? deg[idx] : 0;
    loc[j] = s;
    s += v;
  }
  ps[t] = s;
  __syncthreads();
  for (int off = 1; off < 1024; off <<= 1) {
    int x = (t >= off) ? ps[t - off] : 0;
    __syncthreads();
    ps[t] += x;
    __syncthreads();
  }
  const int excl = ps[t] - s;
#pragma unroll
  for (int j = 0; j < 20; ++j) {
    int idx = base + j;
    if (idx < NN) rs[idx] = excl + loc[j];
  }
  if (t == 1023) rs[NN] = ps[1023];
}

__global__ void fill_csr(const int* __restrict__ src, const int* __restrict__ dst,
                         const int* __restrict__ rs, int* __restrict__ cur,
                         int* __restrict__ eidx, int2* __restrict__ gsd) {
  int e = blockIdx.x * 256 + threadIdx.x;
  if (e < EE) {
    int d = dst[e];
    int p = atomicAdd(&cur[d], 1);
    int o = rs[d] + p;
    eidx[o] = e;
    gsd[o] = make_int2(src[e], d);
  }
}

// ---------------- all weight transposes in one kernel -----------------------
__global__ void transpose_all(const float* __restrict__ encW0, const float* __restrict__ encW,
                              const float* __restrict__ clsW0, const float* __restrict__ clsW,
                              const float* __restrict__ eaW1, ushort* __restrict__ Wt) {
  int i = blockIdx.x * 256 + threadIdx.x;
  if (i < 8192) {
    int k = i >> 7, n = i & 127;
    Wt[WT_ENC0 + n * 64 + k] = f2bf(encW0[i]);
  } else if (i < 73728) {
    int j = i - 8192;
    int l = j >> 14, r = j & 16383, k = r >> 7, n = r & 127;
    Wt[WT_ENC + l * 16384 + n * 128 + k] = f2bf(encW[j]);
  } else if (i < 81920) {
    int j = i - 73728;
    int k = j >> 7, n = j & 127;
    Wt[WT_CLS0 + n * 64 + k] = f2bf(clsW0[j]);
  } else if (i < 147456) {
    int j = i - 81920;
    int l = j >> 14, r = j & 16383, k = r >> 7, n = r & 127;
    Wt[WT_CLS + l * 16384 + n * 128 + k] = f2bf(clsW[j]);
  } else if (i < 278528) {
    int j = i - 147456;
    int k = j >> 9, n = j & 511;
    Wt[WT_EA1 + n * 256 + k] = f2bf(eaW1[j]);
  }
}

// ---------------- fused GIN layer, K=64 (fp32 x in, bf16 out) ---------------
// 16 nodes/block; 32 groups of 8 lanes = 2 split-chains per node (alternate
// edges), register accumulate, two LDS partial buffers (no atomics).
template <bool USEDL>
__global__ __launch_bounds__(256) void fused_layer64(
    const float* __restrict__ X, ushort* __restrict__ C,
    const int2* __restrict__ gsd, const int* __restrict__ rs,
    const float* __restrict__ dl, const float* __restrict__ scal,
    const ushort* __restrict__ Bt, const float* __restrict__ bias) {
  __shared__ __align__(16) char smem[16896];
  float* accF = (float*)smem;                 // [2][16][68] = 8704 B
  const int tid = threadIdx.x;
  const int nb = blockIdx.x * 16;
  const int g = tid >> 3, l = tid & 7;
  const int nl = g >> 1, h = g & 1;
  const int n = nb + nl;
  float S = 0.f, sc = 1.f;
  if (USEDL) { S = scal[8]; sc = scal[9]; }
  float a[8];
  if (h == 0) {
    const float4* Xr = (const float4*)(X + (size_t)n * 64 + l * 8);
    float4 s0 = Xr[0], s1 = Xr[1];
    a[0] = s0.x; a[1] = s0.y; a[2] = s0.z; a[3] = s0.w;
    a[4] = s1.x; a[5] = s1.y; a[6] = s1.z; a[7] = s1.w;
  } else {
#pragma unroll
    for (int j = 0; j < 8; ++j) a[j] = 0.f;
  }
  const int e1 = rs[n + 1];
  int iA = rs[n] + h, iB = iA + 2;
  float rA = 0.f, rB = 0.f;
  float4 a0, a1, b0, b1;
  if (iA < e1) {
    int s = gsd[iA].x;
    if (USEDL) rA = dl[iA];
    const float4* R = (const float4*)(X + (size_t)s * 64 + l * 8);
    a0 = R[0]; a1 = R[1];
  }
  if (iB < e1) {
    int s = gsd[iB].x;
    if (USEDL) rB = dl[iB];
    const float4* R = (const float4*)(X + (size_t)s * 64 + l * 8);
    b0 = R[0]; b1 = R[1];
  }
  while (iA < e1) {
    int iC = iB + 2;
    float rC = 0.f;
    float4 c0, c1;
    if (iC < e1) {
      int s = gsd[iC].x;
      if (USEDL) rC = dl[iC];
      const float4* R = (const float4*)(X + (size_t)s * 64 + l * 8);
      c0 = R[0]; c1 = R[1];
    }
    float w = 1.f;
    if (USEDL) w = sc / (1.f + __expf(-(rA + S)));
    a[0] = fmaf(w, a0.x, a[0]); a[1] = fmaf(w, a0.y, a[1]);
    a[2] = fmaf(w, a0.z, a[2]); a[3] = fmaf(w, a0.w, a[3]);
    a[4] = fmaf(w, a1.x, a[4]); a[5] = fmaf(w, a1.y, a[5]);
    a[6] = fmaf(w, a1.z, a[6]); a[7] = fmaf(w, a1.w, a[7]);
    iA = iB; rA = rB; a0 = b0; a1 = b1;
    iB = iC; rB = rC; b0 = c0; b1 = c1;
  }
  {
    float* dp = accF + (h * 16 + nl) * 68 + l * 8;
    *(f32x4*)dp = f32x4{a[0], a[1], a[2], a[3]};
    *(f32x4*)(dp + 4) = f32x4{a[4], a[5], a[6], a[7]};
  }
  __syncthreads();
  const int wave = tid >> 6, lane = tid & 63, quad = lane >> 4, l15 = lane & 15;
  f32x4 acc2[2] = {{0.f, 0.f, 0.f, 0.f}, {0.f, 0.f, 0.f, 0.f}};
#pragma unroll
  for (int k0 = 0; k0 < 64; k0 += 32) {
    const float* p0 = accF + l15 * 68 + k0 + quad * 8;
    const float* p1 = accF + (16 + l15) * 68 + k0 + quad * 8;
    f32x4 u0 = *(const f32x4*)p0, u1 = *(const f32x4*)(p0 + 4);
    f32x4 v0 = *(const f32x4*)p1, v1 = *(const f32x4*)(p1 + 4);
    bf16x8 af;
    af[0] = (short)f2bf(u0[0] + v0[0]); af[1] = (short)f2bf(u0[1] + v0[1]);
    af[2] = (short)f2bf(u0[2] + v0[2]); af[3] = (short)f2bf(u0[3] + v0[3]);
    af[4] = (short)f2bf(u1[0] + v1[0]); af[5] = (short)f2bf(u1[1] + v1[1]);
    af[6] = (short)f2bf(u1[2] + v1[2]); af[7] = (short)f2bf(u1[3] + v1[3]);
#pragma unroll
    for (int t = 0; t < 2; ++t) {
      int bn = wave * 32 + t * 16 + l15;
      bf16x8 bf = *(const bf16x8*)(Bt + (size_t)bn * 64 + k0 + quad * 8);
      acc2[t] = __builtin_amdgcn_mfma_f32_16x16x32_bf16(af, bf, acc2[t], 0, 0, 0);
    }
  }
  __syncthreads();
  float (*Csm)[132] = (float(*)[132])smem;
#pragma unroll
  for (int t = 0; t < 2; ++t) {
    int lc = wave * 32 + t * 16 + l15;
    float bs = bias[lc];
#pragma unroll
    for (int r = 0; r < 4; ++r)
      Csm[quad * 4 + r][lc] = fmaxf(acc2[t][r] + bs, 0.f);
  }
  __syncthreads();
  const int r = tid >> 4, c0 = (tid & 15) * 8;
  f32x4 v0 = *(const f32x4*)&Csm[r][c0];
  f32x4 v1 = *(const f32x4*)&Csm[r][c0 + 4];
  uint4 o;
  o.x = pack2(v0[0], v0[1]); o.y = pack2(v0[2], v0[3]);
  o.z = pack2(v1[0], v1[1]); o.w = pack2(v1[2], v1[3]);
  *(uint4*)(C + (size_t)(nb + r) * 128 + c0) = o;
}

// ---------------- fused GIN layer, K=128 (bf16 in/out) ----------------------
template <bool USEDL>
__global__ __launch_bounds__(256) void fused_layer128(
    const ushort* __restrict__ Xb, ushort* __restrict__ C,
    const int2* __restrict__ gsd, const int* __restrict__ rs,
    const float* __restrict__ dl, const float* __restrict__ scal,
    const ushort* __restrict__ Bt, const float* __restrict__ bias) {
  __shared__ __align__(16) char smem[16896];
  float* accF = (float*)smem;                 // [2][16][132] = 16896 B
  const int tid = threadIdx.x;
  const int nb = blockIdx.x * 16;
  const int g = tid >> 3, l = tid & 7;
  const int nl = g >> 1, h = g & 1;
  const int n = nb + nl;
  float S = 0.f, sc = 1.f;
  if (USEDL) { S = scal[8]; sc = scal[9]; }
  float a[16];
  if (h == 0) {
    const uint4* Xr = (const uint4*)(Xb + (size_t)n * 128 + l * 16);
    uint4 s0 = Xr[0], s1 = Xr[1];
    a[0] = bflo(s0.x); a[1] = bfhi(s0.x); a[2] = bflo(s0.y); a[3] = bfhi(s0.y);
    a[4] = bflo(s0.z); a[5] = bfhi(s0.z); a[6] = bflo(s0.w); a[7] = bfhi(s0.w);
    a[8] = bflo(s1.x); a[9] = bfhi(s1.x); a[10] = bflo(s1.y); a[11] = bfhi(s1.y);
    a[12] = bflo(s1.z); a[13] = bfhi(s1.z); a[14] = bflo(s1.w); a[15] = bfhi(s1.w);
  } else {
#pragma unroll
    for (int j = 0; j < 16; ++j) a[j] = 0.f;
  }
  const int e1 = rs[n + 1];
  int iA = rs[n] + h, iB = iA + 2;
  float rA = 0.f, rB = 0.f;
  uint4 a0, a1, b0, b1;
  if (iA < e1) {
    int s = gsd[iA].x;
    if (USEDL) rA = dl[iA];
    const uint4* R = (const uint4*)(Xb + (size_t)s * 128 + l * 16);
    a0 = R[0]; a1 = R[1];
  }
  if (iB < e1) {
    int s = gsd[iB].x;
    if (USEDL) rB = dl[iB];
    const uint4* R = (const uint4*)(Xb + (size_t)s * 128 + l * 16);
    b0 = R[0]; b1 = R[1];
  }
  while (iA < e1) {
    int iC = iB + 2;
    float rC = 0.f;
    uint4 c0, c1;
    if (iC < e1) {
      int s = gsd[iC].x;
      if (USEDL) rC = dl[iC];
      const uint4* R = (const uint4*)(Xb + (size_t)s * 128 + l * 16);
      c0 = R[0]; c1 = R[1];
    }
    float w = 1.f;
    if (USEDL) w = sc / (1.f + __expf(-(rA + S)));
    a[0] = fmaf(w, bflo(a0.x), a[0]);  a[1] = fmaf(w, bfhi(a0.x), a[1]);
    a[2] = fmaf(w, bflo(a0.y), a[2]);  a[3] = fmaf(w, bfhi(a0.y), a[3]);
    a[4] = fmaf(w, bflo(a0.z), a[4]);  a[5] = fmaf(w, bfhi(a0.z), a[5]);
    a[6] = fmaf(w, bflo(a0.w), a[6]);  a[7] = fmaf(w, bfhi(a0.w), a[7]);
    a[8] = fmaf(w, bflo(a1.x), a[8]);  a[9] = fmaf(w, bfhi(a1.x), a[9]);
    a[10] = fmaf(w, bflo(a1.y), a[10]); a[11] = fmaf(w, bfhi(a1.y), a[11]);
    a[12] = fmaf(w, bflo(a1.z), a[12]); a[13] = fmaf(w, bfhi(a1.z), a[13]);
    a[14] = fmaf(w, bflo(a1.w), a[14]); a[15] = fmaf(w, bfhi(a1.w), a[15]);
    iA = iB; rA = rB; a0 = b0; a1 = b1;
    iB = iC; rB = rC; b0 = c0; b1 = c1;
  }
  {
    float* dp = accF + (h * 16 + nl) * 132 + l * 16;
    *(f32x4*)dp = f32x4{a[0], a[1], a[2], a[3]};
    *(f32x4*)(dp + 4) = f32x4{a[4], a[5], a[6], a[7]};
    *(f32x4*)(dp + 8) = f32x4{a[8], a[9], a[10], a[11]};
    *(f32x4*)(dp + 12) = f32x4{a[12], a[13], a[14], a[15]};
  }
  __syncthreads();
  const int wave = tid >> 6, lane = tid & 63, quad = lane >> 4, l15 = lane & 15;
  f32x4 acc2[2] = {{0.f, 0.f, 0.f, 0.f}, {0.f, 0.f, 0.f, 0.f}};
#pragma unroll
  for (int k0 = 0; k0 < 128; k0 += 32) {
    const float* p0 = accF + l15 * 132 + k0 + quad * 8;
    const float* p1 = accF + (16 + l15) * 132 + k0 + quad * 8;
    f32x4 u0 = *(const f32x4*)p0, u1 = *(const f32x4*)(p0 + 4);
    f32x4 v0 = *(const f32x4*)p1, v1 = *(const f32x4*)(p1 + 4);
    bf16x8 af;
    af[0] = (short)f2bf(u0[0] + v0[0]); af[1] = (short)f2bf(u0[1] + v0[1]);
    af[2] = (short)f2bf(u0[2] + v0[2]); af[3] = (short)f2bf(u0[3] + v0[3]);
    af[4] = (short)f2bf(u1[0] + v1[0]); af[5] = (short)f2bf(u1[1] + v1[1]);
    af[6] = (short)f2bf(u1[2] + v1[2]); af[7] = (short)f2bf(u1[3] + v1[3]);
#pragma unroll
    for (int t = 0; t < 2; ++t) {
      int bn = wave * 32 + t * 16 + l15;
      bf16x8 bf = *(const bf16x8*)(Bt + (size_t)bn * 128 + k0 + quad * 8);
      acc2[t] = __builtin_amdgcn_mfma_f32_16x16x32_bf16(af, bf, acc2[t], 0, 0, 0);
    }
  }
  __syncthreads();
  float (*Csm)[132] = (float(*)[132])smem;
#pragma unroll
  for (int t = 0; t < 2; ++t) {
    int lc = wave * 32 + t * 16 + l15;
    float bs = bias[lc];
#pragma unroll
    for (int r = 0; r < 4; ++r)
      Csm[quad * 4 + r][lc] = fmaxf(acc2[t][r] + bs, 0.f);
  }
  __syncthreads();
  const int r = tid >> 4, c0 = (tid & 15) * 8;
  f32x4 v0 = *(const f32x4*)&Csm[r][c0];
  f32x4 v1 = *(const f32x4*)&Csm[r][c0 + 4];
  uint4 o;
  o.x = pack2(v0[0], v0[1]); o.y = pack2(v0[2], v0[3]);
  o.z = pack2(v1[0], v1[1]); o.w = pack2(v1[2], v1[3]);
  *(uint4*)(C + (size_t)(nb + r) * 128 + c0) = o;
}

// ---------------- Pa/Pb GEMM, bf16 output: grid (8, 625) --------------------
__global__ __launch_bounds__(256) void gemm_papb(
    const ushort* __restrict__ Hb, const ushort* __restrict__ W1t,
    const float* __restrict__ b1, ushort* __restrict__ Pa, ushort* __restrict__ Pb) {
  __shared__ float lds[32][132];
  const int tid = threadIdx.x;
  const int wave = tid >> 6, lane = tid & 63, quad = lane >> 4, l15 = lane & 15;
  const int mh = wave >> 1, nh = wave & 1;
  const bool isB = blockIdx.x >= 4;
  const int col0 = (blockIdx.x & 3) * 128;
  const int row0 = blockIdx.y * 32;
  const ushort* Bt = W1t + (isB ? 128 : 0);
  ushort* C = isB ? Pb : Pa;
  f32x4 acc[4] = {{0.f, 0.f, 0.f, 0.f}, {0.f, 0.f, 0.f, 0.f},
                  {0.f, 0.f, 0.f, 0.f}, {0.f, 0.f, 0.f, 0.f}};
  const ushort* Ap = Hb + (size_t)(row0 + mh * 16 + l15) * 128 + quad * 8;
#pragma unroll
  for (int k0 = 0; k0 < 128; k0 += 32) {
    bf16x8 af = *(const bf16x8*)(Ap + k0);
#pragma unroll
    for (int t = 0; t < 4; ++t) {
      int bn = col0 + nh * 64 + t * 16 + l15;
      bf16x8 bf = *(const bf16x8*)(Bt + (size_t)bn * 256 + k0 + quad * 8);
      acc[t] = __builtin_amdgcn_mfma_f32_16x16x32_bf16(af, bf, acc[t], 0, 0, 0);
    }
  }
#pragma unroll
  for (int t = 0; t < 4; ++t) {
    int lc = nh * 64 + t * 16 + l15;
    float bs = isB ? 0.f : b1[col0 + lc];
#pragma unroll
    for (int r = 0; r < 4; ++r)
      lds[mh * 16 + quad * 4 + r][lc] = acc[t][r] + bs;
  }
  __syncthreads();
  const int r = tid >> 3, c0 = (tid & 7) * 16;
  ushort* Cp = C + (size_t)(row0 + r) * 512 + col0 + c0;
#pragma unroll
  for (int k = 0; k < 4; ++k) {
    f32x4 v = *(const f32x4*)&lds[r][c0 + k * 4];
    ushort4 o;
    o.x = f2bf(v[0]); o.y = f2bf(v[1]); o.z = f2bf(v[2]); o.w = f2bf(v[3]);
    *(ushort4*)(Cp + k * 4) = o;
  }
}

// ---------------- edge MLP layer 2 (bf16), edge-parallel + fused stats ------
__global__ __launch_bounds__(256) void edge_pe_csr(
    const ushort* __restrict__ Pa, const ushort* __restrict__ Pb,
    const int2* __restrict__ gsd, const int* __restrict__ rs,
    const float* __restrict__ W2, const float* __restrict__ b2,
    float* __restrict__ pe, float* __restrict__ scal) {
  __shared__ float st[8][4];
  const int tid = threadIdx.x;
  const int hl = tid & 31;
  const int hw = tid >> 5;
  const int nb = blockIdx.x * 8;
  float w[16];
  {
    const float4* w2v = (const float4*)(W2 + hl * 16);
#pragma unroll
    for (int q = 0; q < 4; ++q) {
      float4 t = w2v[q];
      w[q * 4 + 0] = t.x; w[q * 4 + 1] = t.y; w[q * 4 + 2] = t.z; w[q * 4 + 3] = t.w;
    }
  }
  const float b2v = b2[0];
  const int eEnd = rs[nb + 8];
  float s = 0.f, qq = 0.f, mn = 3.0e38f, mx = -3.0e38f;
  int iA = rs[nb] + hw, iB = iA + 8;
  uint4 aA0, aA1, bA0, bA1, aB0, aB1, bB0, bB1;
  if (iA < eEnd) {
    int2 sd = gsd[iA];
    const uint4* RA = (const uint4*)(Pa + (size_t)sd.x * 512 + hl * 16);
    const uint4* RB = (const uint4*)(Pb + (size_t)sd.y * 512 + hl * 16);
    aA0 = RA[0]; aA1 = RA[1]; bA0 = RB[0]; bA1 = RB[1];
  }
  if (iB < eEnd) {
    int2 sd = gsd[iB];
    const uint4* RA = (const uint4*)(Pa + (size_t)sd.x * 512 + hl * 16);
    const uint4* RB = (const uint4*)(Pb + (size_t)sd.y * 512 + hl * 16);
    aB0 = RA[0]; aB1 = RA[1]; bB0 = RB[0]; bB1 = RB[1];
  }
  while (iA < eEnd) {
    int iC = iB + 8;
    uint4 aC0, aC1, bC0, bC1;
    if (iC < eEnd) {
      int2 sd = gsd[iC];
      const uint4* RA = (const uint4*)(Pa + (size_t)sd.x * 512 + hl * 16);
      const uint4* RB = (const uint4*)(Pb + (size_t)sd.y * 512 + hl * 16);
      aC0 = RA[0]; aC1 = RA[1]; bC0 = RB[0]; bC1 = RB[1];
    }
    float pa[16], pb[16];
    pa[0] = bflo(aA0.x); pa[1] = bfhi(aA0.x); pa[2] = bflo(aA0.y); pa[3] = bfhi(aA0.y);
    pa[4] = bflo(aA0.z); pa[5] = bfhi(aA0.z); pa[6] = bflo(aA0.w); pa[7] = bfhi(aA0.w);
    pa[8] = bflo(aA1.x); pa[9] = bfhi(aA1.x); pa[10] = bflo(aA1.y); pa[11] = bfhi(aA1.y);
    pa[12] = bflo(aA1.z); pa[13] = bfhi(aA1.z); pa[14] = bflo(aA1.w); pa[15] = bfhi(aA1.w);
    pb[0] = bflo(bA0.x); pb[1] = bfhi(bA0.x); pb[2] = bflo(bA0.y); pb[3] = bfhi(bA0.y);
    pb[4] = bflo(bA0.z); pb[5] = bfhi(bA0.z); pb[6] = bflo(bA0.w); pb[7] = bfhi(bA0.w);
    pb[8] = bflo(bA1.x); pb[9] = bfhi(bA1.x); pb[10] = bflo(bA1.y); pb[11] = bfhi(bA1.y);
    pb[12] = bflo(bA1.z); pb[13] = bfhi(bA1.z); pb[14] = bflo(bA1.w); pb[15] = bfhi(bA1.w);
    float acc = 0.f;
#pragma unroll
    for (int j = 0; j < 16; ++j) acc += fmaxf(pa[j] + pb[j], 0.f) * w[j];
#pragma unroll
    for (int off = 16; off; off >>= 1) acc += __shfl_xor(acc, off);
    if (hl == 0) {
      float v = acc + b2v;
      pe[iA] = v;
      s += v; qq = fmaf(v, v, qq);
      mn = fminf(mn, v); mx = fmaxf(mx, v);
    }
    iA = iB; aA0 = aB0; aA1 = aB1; bA0 = bB0; bA1 = bB1;
    iB = iC; aB0 = aC0; aB1 = aC1; bB0 = bC0; bB1 = bC1;
  }
  if (hl == 0) { st[hw][0] = s; st[hw][1] = qq; st[hw][2] = mn; st[hw][3] = mx; }
  __syncthreads();
  if (tid == 0) {
    float ts = 0.f, tq = 0.f, tm = 3.0e38f, tM = -3.0e38f;
#pragma unroll
    for (int k = 0; k < 8; ++k) {
      ts += st[k][0]; tq += st[k][1];
      tm = fminf(tm, st[k][2]); tM = fmaxf(tM, st[k][3]);
    }
    unsafeAtomicAdd(&scal[0], ts);
    unsafeAtomicAdd(&scal[1], tq);
    atomicMin((unsigned*)scal + 2, ordf(tm));
    atomicMax((unsigned*)scal + 3, ordf(tM));
  }
}

// ---------------- delta + histogram (CSR order; u gathered via eidx) --------
__global__ __launch_bounds__(256) void edge_delta_hist(
    const float* __restrict__ pe, const float* __restrict__ u,
    const int* __restrict__ eidx, float* __restrict__ delta,
    float* __restrict__ hist, const float* __restrict__ scal) {
  __shared__ float cnt_s[NBINS], sum_s[NBINS];
  for (int b = threadIdx.x; b < NBINS; b += 256) { cnt_s[b] = 0.f; sum_s[b] = 0.f; }
  float sum = scal[0], ssq = scal[1];
  float mn = unordf(((const unsigned*)scal)[2]);
  float mx = unordf(((const unsigned*)scal)[3]);
  float mu = sum / (float)EE;
  float var = (ssq - sum * sum / (float)EE) / (float)(EE - 1);
  float istd = rsqrtf(fmaxf(var, 1e-30f));
  float shift = (mn - mu) * istd + (mx - mu) * istd;
  __syncthreads();
  for (int i = blockIdx.x * 256 + threadIdx.x; i < EE; i += gridDim.x * 256) {
    float uu = u[eidx[i]];
    float atts = (pe[i] - mu) * istd;
    float g = -logf(-logf(uu + EPSF) + EPSF);
    float dv = 2.0f * (atts + g) - shift;
    delta[i] = dv;
    float dcl = fminf(fmaxf(dv, -HRANGE), HRANGE * 0.9999f);
    int b = (int)((dcl + HRANGE) * ((float)NBINS / (2.0f * HRANGE)));
    b = min(max(b, 0), NBINS - 1);
    atomicAdd(&cnt_s[b], 1.0f);
    atomicAdd(&sum_s[b], dcl);
  }
  __syncthreads();
  for (int b = threadIdx.x; b < NBINS; b += 256) {
    float c = cnt_s[b];
    if (c != 0.f) {
      unsafeAtomicAdd(&hist[b], c);
      unsafeAtomicAdd(&hist[NBINS + b], sum_s[b]);
    }
  }
}

// ---------------- scalar Sinkhorn recursion (single wave) -------------------
__global__ __launch_bounds__(64) void sinkhorn_iter(const float* __restrict__ hist,
                                                    float* __restrict__ scal) {
  const int lane = threadIdx.x;
  float cnt[32], mean[32];
#pragma unroll
  for (int b = 0; b < 32; ++b) {
    int idx = b * 64 + lane;
    float c = hist[idx];
    cnt[b] = c;
    mean[b] = (c > 0.f) ? hist[NBINS + idx] / c : 0.f;
  }
  const float LRD = -1.0986122886681098f;
  float S = 0.f, Zfin = 0.f;
  for (int it = 0; it < 30; ++it) {
    float p = 0.f;
#pragma unroll
    for (int b = 0; b < 32; ++b)
      if (cnt[b] > 0.f) p += cnt[b] / (1.f + expf(-(mean[b] + S)));
#pragma unroll
    for (int off = 32; off; off >>= 1) p += __shfl_xor(p, off);
    if (it < 29)
      S += logf(fmaxf((float)EE - p, 1.0f)) - logf(p) + LRD;
    else
      Zfin = p;
  }
  if (lane == 0) {
    scal[8] = S;
    scal[9] = ((float)EE * 0.25f) / Zfin;
  }
}

// ---------------- mean pooling + head ---------------------------------------
__global__ __launch_bounds__(128) void col_mean(const ushort* __restrict__ Hc,
                                                float* __restrict__ rep) {
  int c = threadIdx.x;
  const int g = gridDim.x;
  float p0 = 0.f, p1 = 0.f, p2 = 0.f, p3 = 0.f;
  int n = blockIdx.x;
  for (; n + 3 * g < NN; n += 4 * g) {
    p0 += bf2f(Hc[(size_t)n * 128 + c]);
    p1 += bf2f(Hc[(size_t)(n + g) * 128 + c]);
    p2 += bf2f(Hc[(size_t)(n + 2 * g) * 128 + c]);
    p3 += bf2f(Hc[(size_t)(n + 3 * g) * 128 + c]);
  }
  for (; n < NN; n += g) p0 += bf2f(Hc[(size_t)n * 128 + c]);
  unsafeAtomicAdd(&rep[c], (p0 + p1) + (p2 + p3));
}

__global__ __launch_bounds__(128) void head_kernel(const float* __restrict__ repsum,
                                                   const float* __restrict__ hW,
                                                   const float* __restrict__ hb,
                                                   float* __restrict__ out) {
  __shared__ float rep[128];
  int tid = threadIdx.x;
  if (tid < 128) rep[tid] = repsum[tid] * (1.0f / (float)NN);
  __syncthreads();
  if (tid < 10) {
    float a = hb[tid];
#pragma unroll
    for (int c = 0; c < 128; c++) a = fmaf(rep[c], hW[c * 10 + tid], a);
    out[tid] = a;
  }
}

// ---------------- launch ----------------------------------------------------
extern "C" void kernel_launch(void* const* d_in, const int* in_sizes, int n_in,
                              void* d_out, int out_size, void* d_ws, size_t ws_size,
                              hipStream_t stream) {
  const float* x      = (const float*)d_in[0];
  const int*   ei     = (const int*)d_in[1];
  const float* u      = (const float*)d_in[2];
  const float* enc_W0 = (const float*)d_in[3];
  const float* enc_b0 = (const float*)d_in[4];
  const float* enc_W  = (const float*)d_in[5];
  const float* enc_b  = (const float*)d_in[6];
  const float* ea_W1  = (const float*)d_in[7];
  const float* ea_b1  = (const float*)d_in[8];
  const float* ea_W2  = (const float*)d_in[9];
  const float* ea_b2  = (const float*)d_in[10];
  const float* cls_W0 = (const float*)d_in[11];
  const float* cls_b0 = (const float*)d_in[12];
  const float* cls_W  = (const float*)d_in[13];
  const float* cls_b  = (const float*)d_in[14];
  const float* head_W = (const float*)d_in[15];
  const float* head_b = (const float*)d_in[16];
  const int* src  = ei;
  const int* dstp = ei + EE;

  float* wsF = (float*)d_ws;
  int*   wsI = (int*)d_ws;
  int* deg  = wsI + OFF_DEG;
  int* rs   = wsI + OFF_RS;
  int* cur  = wsI + OFF_CUR;
  int* eix  = wsI + OFF_EIX;
  int2* gsd = (int2*)(wsI + OFF_GSD);
  ushort* B0 = (ushort*)(wsF + OFF_B0);
  ushort* B1 = (ushort*)(wsF + OFF_B1);
  ushort* Pa = (ushort*)(wsF + OFF_PA);
  ushort* Pb = (ushort*)(wsF + OFF_PB);
  float* pe   = wsF + OFF_PE;
  float* dl   = wsF + OFF_DL;
  float* hist = wsF + OFF_HIST;
  float* scal = wsF + OFF_SCAL;
  float* rep  = wsF + OFF_REP;
  ushort* Wt  = (ushort*)(wsF + OFF_WT);
  float* out = (float*)d_out;

  init_ws<<<(NN + 255) / 256, 256, 0, stream>>>(deg, cur, hist, scal, rep);
  count_deg<<<(EE + 255) / 256, 256, 0, stream>>>(dstp, deg);
  scan_deg<<<1, 1024, 0, stream>>>(deg, rs);
  fill_csr<<<(EE + 255) / 256, 256, 0, stream>>>(src, dstp, rs, cur, eix, gsd);
  transpose_all<<<1088, 256, 0, stream>>>(enc_W0, enc_W, cls_W0, cls_W, ea_W1, Wt);

  const int GB = NN / 16;  // 1250

  // encoder GIN stack (att = 1)
  fused_layer64<false><<<GB, 256, 0, stream>>>(x, B0, gsd, rs, nullptr, scal,
                                               Wt + WT_ENC0, enc_b0);
  {
    ushort* in = B0; ushort* outb = B1;
    for (int l = 0; l < 4; l++) {
      fused_layer128<false><<<GB, 256, 0, stream>>>(in, outb, gsd, rs, nullptr, scal,
                                                    Wt + WT_ENC + (size_t)l * 16384,
                                                    enc_b + (size_t)l * 128);
      ushort* t = in; in = outb; outb = t;
    }
  }
  // encoder output in B0

  gemm_papb<<<dim3(8, NN / 32), 256, 0, stream>>>(B0, Wt + WT_EA1, ea_b1, Pa, Pb);
  edge_pe_csr<<<NN / 8, 256, 0, stream>>>(Pa, Pb, gsd, rs, ea_W2, ea_b2, pe, scal);

  edge_delta_hist<<<256, 256, 0, stream>>>(pe, u, eix, dl, hist, scal);
  sinkhorn_iter<<<1, 64, 0, stream>>>(hist, scal);

  // classifier GIN stack (att = sc*sigmoid(dl+S), computed inline)
  fused_layer64<true><<<GB, 256, 0, stream>>>(x, B0, gsd, rs, dl, scal,
                                              Wt + WT_CLS0, cls_b0);
  {
    ushort* in = B0; ushort* outb = B1;
    for (int l = 0; l < 4; l++) {
      fused_layer128<true><<<GB, 256, 0, stream>>>(in, outb, gsd, rs, dl, scal,
                                                   Wt + WT_CLS + (size_t)l * 16384,
                                                   cls_b + (size_t)l * 128);
      ushort* t = in; in = outb; outb = t;
    }
  }

  col_mean<<<256, 128, 0, stream>>>(B0, rep);
  head_kernel<<<1, 128, 0, stream>>>(rep, head_W, head_b, out);
}